// Round 1
// baseline (298.268 us; speedup 1.0000x reference)
//
#include <hip/hip_runtime.h>
#include <cstddef>
#include <cstdint>

#define T_SEQ 2048
#define EMB_D 2048
#define HD_D  128
#define B_SZ  4

typedef __attribute__((ext_vector_type(8))) short short8;
typedef __attribute__((ext_vector_type(4))) float f32x4;
typedef __attribute__((ext_vector_type(4))) unsigned short ushort4v;

static __device__ __forceinline__ unsigned short f2bf(float f) {
    union { float f; unsigned u; } v; v.f = f;
    unsigned r = v.u + 0x7fffu + ((v.u >> 16) & 1u);   // round-to-nearest-even
    return (unsigned short)(r >> 16);
}

// ---------------------------------------------------------------------------
// Kernel 0: transpose + bf16-convert weights: Wt[w][n][k] = W_w[k][n]
// ---------------------------------------------------------------------------
__global__ __launch_bounds__(256) void prep_weights(
    const float* __restrict__ Wq, const float* __restrict__ Wk,
    const float* __restrict__ Wv, unsigned short* __restrict__ Wt)
{
    const int w = blockIdx.y;
    const float* W = (w == 0) ? Wq : (w == 1) ? Wk : Wv;
    const int idx = blockIdx.x * 256 + threadIdx.x;   // over 128*2048
    const int n = idx >> 11;
    const int k = idx & 2047;
    Wt[(size_t)w * (HD_D * EMB_D) + idx] = f2bf(W[k * HD_D + n]);
}

// ---------------------------------------------------------------------------
// Kernel 1: QKV projection (bf16 MFMA) + RoPE epilogue.
//   grid (64, 3): 64 row-tiles of 128, w = 0(Q)/1(K)/2(V)
//   Q pre-scaled by 1/sqrt(128). V stored transposed Vt[b][d][t].
// ---------------------------------------------------------------------------
__global__ __launch_bounds__(256) void qkv_rope(
    const float* __restrict__ x, const unsigned short* __restrict__ Wt,
    const float* __restrict__ rcos, const float* __restrict__ rsin,
    unsigned short* __restrict__ Qb, unsigned short* __restrict__ Kb,
    unsigned short* __restrict__ Vt)
{
    __shared__ unsigned short xa[128 * 32];   // x tile, row-major [m][k], 8 KB
    const int w    = blockIdx.y;
    const int m0   = blockIdx.x * 128;
    const int tid  = threadIdx.x;
    const int lane = tid & 63;
    const int wave = tid >> 6;
    const int wm = wave >> 1, wn = wave & 1;
    const int l15 = lane & 15, lq = lane >> 4;
    const unsigned short* Wb = Wt + (size_t)w * (HD_D * EMB_D);

    f32x4 acc[4][4];
#pragma unroll
    for (int i = 0; i < 4; i++)
#pragma unroll
        for (int j = 0; j < 4; j++) acc[i][j] = (f32x4){0.f, 0.f, 0.f, 0.f};

    const int srow = tid >> 3;        // 0..31
    const int skc  = (tid & 7) * 4;   // k offset (floats)

    for (int k0 = 0; k0 < EMB_D; k0 += 32) {
        __syncthreads();
#pragma unroll
        for (int p = 0; p < 4; p++) {
            const int r = srow + p * 32;
            const float4 v = *(const float4*)(x + (size_t)(m0 + r) * EMB_D + k0 + skc);
            ushort4v h = { f2bf(v.x), f2bf(v.y), f2bf(v.z), f2bf(v.w) };
            *(ushort4v*)&xa[r * 32 + skc] = h;
        }
        __syncthreads();
        const int kf = lq * 8;
        short8 a[4], b[4];
#pragma unroll
        for (int i = 0; i < 4; i++)
            a[i] = *(const short8*)&xa[(wm * 64 + i * 16 + l15) * 32 + kf];
#pragma unroll
        for (int j = 0; j < 4; j++)
            b[j] = *(const short8*)&Wb[(size_t)(wn * 64 + j * 16 + l15) * EMB_D + k0 + kf];
#pragma unroll
        for (int i = 0; i < 4; i++)
#pragma unroll
            for (int j = 0; j < 4; j++)
                acc[i][j] = __builtin_amdgcn_mfma_f32_16x16x32_bf16(a[i], b[j], acc[i][j], 0, 0, 0);
    }

    // Epilogue: C/D layout row=(lane>>4)*4+reg (m), col=lane&15 (n)
#pragma unroll
    for (int i = 0; i < 4; i++) {
#pragma unroll
        for (int r = 0; r < 4; r++) {
            const int row = m0 + wm * 64 + i * 16 + lq * 4 + r;  // global row (b*T + t)
            const int t = row & (T_SEQ - 1);
#pragma unroll
            for (int j = 0; j < 4; j++) {
                const int col = wn * 64 + j * 16 + l15;
                const float v = acc[i][j][r];
                if (w == 2) {
                    const int bb = row >> 11;
                    Vt[((size_t)bb * HD_D + col) * T_SEQ + t] = f2bf(v);
                } else {
                    const int ip = col >> 1;
                    const float c = rcos[t * 64 + ip];
                    const float s = rsin[t * 64 + ip];
                    const float pv = __shfl_xor(v, 1);  // pair partner (col^1)
                    float rv = (col & 1) ? (pv * s + v * c) : (v * c - pv * s);
                    if (w == 0) rv *= 0.08838834764831845f;   // 1/sqrt(128)
                    const unsigned short o = f2bf(rv);
                    if (w == 0) Qb[(size_t)row * HD_D + col] = o;
                    else        Kb[(size_t)row * HD_D + col] = o;
                }
            }
        }
    }
}

// ---------------------------------------------------------------------------
// Kernel 2: flash attention, causal, online softmax.
//   1 wave per block, 16 q-rows per block; grid (128, 4).
// ---------------------------------------------------------------------------
__global__ __launch_bounds__(64) void attn(
    const unsigned short* __restrict__ Qb, const unsigned short* __restrict__ Kb,
    const unsigned short* __restrict__ Vt, float* __restrict__ out)
{
    __shared__ unsigned short P[16 * 32];   // P tile (bf16), C-layout -> A-layout bridge
    const int lane = threadIdx.x;
    const int l15 = lane & 15, lq = lane >> 4;
    const int kf = lq * 8;
    const int b  = blockIdx.y;
    const int q0 = blockIdx.x * 16;

    // Q fragments (A layout): rows q0..q0+15, 4 d-chunks of 32
    const unsigned short* Qp = Qb + (size_t)(b * T_SEQ + q0) * HD_D;
    short8 aQ[4];
#pragma unroll
    for (int d = 0; d < 4; d++)
        aQ[d] = *(const short8*)&Qp[l15 * HD_D + d * 32 + kf];

    f32x4 acc[8];
#pragma unroll
    for (int d = 0; d < 8; d++) acc[d] = (f32x4){0.f, 0.f, 0.f, 0.f};
    float m_r[4] = {-1e30f, -1e30f, -1e30f, -1e30f};
    float l_r[4] = {0.f, 0.f, 0.f, 0.f};

    const unsigned short* Kbase = Kb + (size_t)b * T_SEQ * HD_D;
    const unsigned short* Vbase = Vt + (size_t)b * HD_D * T_SEQ;
    const int kend = q0 + 16;   // max valid k index + 1

    for (int k0 = 0; k0 < kend; k0 += 32) {
        // --- S = Q K^T (pre-scaled), two 16x16 n-halves ---
        f32x4 s0 = (f32x4){0.f, 0.f, 0.f, 0.f};
        f32x4 s1 = (f32x4){0.f, 0.f, 0.f, 0.f};
        const unsigned short* Kp = Kbase + (size_t)k0 * HD_D;
#pragma unroll
        for (int d = 0; d < 4; d++) {
            short8 b0 = *(const short8*)&Kp[l15 * HD_D + d * 32 + kf];
            short8 b1 = *(const short8*)&Kp[(16 + l15) * HD_D + d * 32 + kf];
            s0 = __builtin_amdgcn_mfma_f32_16x16x32_bf16(aQ[d], b0, s0, 0, 0, 0);
            s1 = __builtin_amdgcn_mfma_f32_16x16x32_bf16(aQ[d], b1, s1, 0, 0, 0);
        }
        // --- causal mask + online softmax (C layout: row=lq*4+r, col=l15) ---
        const int kc0 = k0 + l15, kc1 = kc0 + 16;
        float p0[4], p1[4], alpha[4];
#pragma unroll
        for (int r = 0; r < 4; r++) {
            const int q = q0 + lq * 4 + r;
            const float v0 = (kc0 <= q) ? s0[r] : -1e30f;
            const float v1 = (kc1 <= q) ? s1[r] : -1e30f;
            float t = fmaxf(v0, v1);
            t = fmaxf(t, __shfl_xor(t, 1));
            t = fmaxf(t, __shfl_xor(t, 2));
            t = fmaxf(t, __shfl_xor(t, 4));
            t = fmaxf(t, __shfl_xor(t, 8));
            const float mn = fmaxf(m_r[r], t);
            alpha[r] = __expf(m_r[r] - mn);
            p0[r] = __expf(v0 - mn);
            p1[r] = __expf(v1 - mn);
            float rs = p0[r] + p1[r];
            rs += __shfl_xor(rs, 1);
            rs += __shfl_xor(rs, 2);
            rs += __shfl_xor(rs, 4);
            rs += __shfl_xor(rs, 8);
            l_r[r] = l_r[r] * alpha[r] + rs;
            m_r[r] = mn;
        }
#pragma unroll
        for (int d = 0; d < 8; d++)
#pragma unroll
            for (int r = 0; r < 4; r++) acc[d][r] *= alpha[r];

        // --- P: C-layout -> A-layout via LDS (single wave, barriers are cheap) ---
        __syncthreads();
#pragma unroll
        for (int r = 0; r < 4; r++) {
            const int row = lq * 4 + r;
            P[row * 32 + l15]      = f2bf(p0[r]);
            P[row * 32 + 16 + l15] = f2bf(p1[r]);
        }
        __syncthreads();
        const short8 pA = *(const short8*)&P[l15 * 32 + kf];
        // --- O += P V : B frag from transposed V, contiguous 16B ---
#pragma unroll
        for (int d = 0; d < 8; d++) {
            short8 bV = *(const short8*)&Vbase[(size_t)(d * 16 + l15) * T_SEQ + k0 + kf];
            acc[d] = __builtin_amdgcn_mfma_f32_16x16x32_bf16(pA, bV, acc[d], 0, 0, 0);
        }
    }

    // --- normalize + store fp32 out[b][q][d] ---
#pragma unroll
    for (int r = 0; r < 4; r++) {
        const float inv = 1.0f / l_r[r];
        float* op = out + (size_t)(b * T_SEQ + q0 + lq * 4 + r) * HD_D;
#pragma unroll
        for (int d = 0; d < 8; d++)
            op[d * 16 + l15] = acc[d][r] * inv;
    }
}

// ---------------------------------------------------------------------------
extern "C" void kernel_launch(void* const* d_in, const int* in_sizes, int n_in,
                              void* d_out, int out_size, void* d_ws, size_t ws_size,
                              hipStream_t stream)
{
    (void)in_sizes; (void)n_in; (void)out_size; (void)ws_size;
    const float* x  = (const float*)d_in[0];
    const float* Wq = (const float*)d_in[1];
    const float* Wk = (const float*)d_in[2];
    const float* Wv = (const float*)d_in[3];
    const float* rc = (const float*)d_in[4];
    const float* rs = (const float*)d_in[5];
    // d_in[6] = additive causal mask: handled analytically, not read.
    float* out = (float*)d_out;

    char* ws = (char*)d_ws;
    unsigned short* Wt = (unsigned short*)(ws);                           // 1,572,864 B
    unsigned short* Qb = (unsigned short*)(ws + 1572864);                 // 2,097,152 B
    unsigned short* Kb = (unsigned short*)(ws + 1572864 + 2097152);       // 2,097,152 B
    unsigned short* Vt = (unsigned short*)(ws + 1572864 + 2 * 2097152);   // 2,097,152 B

    prep_weights<<<dim3(1024, 3), 256, 0, stream>>>(Wq, Wk, Wv, Wt);
    qkv_rope   <<<dim3(64, 3),   256, 0, stream>>>(x, Wt, rc, rs, Qb, Kb, Vt);
    attn       <<<dim3(128, 4),  64,  0, stream>>>(Qb, Kb, Vt, out);
}

// Round 2
// 233.430 us; speedup vs baseline: 1.2778x; 1.2778x over previous
//
#include <hip/hip_runtime.h>
#include <cstddef>
#include <cstdint>

#define T_SEQ 2048
#define EMB_D 2048
#define HD_D  128

typedef __attribute__((ext_vector_type(8))) short short8;
typedef __attribute__((ext_vector_type(4))) float f32x4;
typedef __attribute__((ext_vector_type(4))) unsigned short ushort4v;
typedef __attribute__((ext_vector_type(8))) unsigned short ushort8v;

static __device__ __forceinline__ unsigned short f2bf_rne(float f) {
    union { float f; unsigned u; } v; v.f = f;
    unsigned r = v.u + 0x7fffu + ((v.u >> 16) & 1u);
    return (unsigned short)(r >> 16);
}
static __device__ __forceinline__ unsigned short f2bf_fast(float f) {
    union { float f; unsigned u; } v; v.f = f;
    return (unsigned short)((v.u + 0x8000u) >> 16);
}
#define EXP2F(x) __builtin_amdgcn_exp2f(x)

// ---------------------------------------------------------------------------
// Kernel 0: coalesced transpose + bf16 convert: Wt[w][n][k] = W_w[k][n]
//   grid (32, 3), 256 thr. LDS tile 64k x 128n (pad 132 for alignment).
// ---------------------------------------------------------------------------
__global__ __launch_bounds__(256) void prep_weights(
    const float* __restrict__ Wq, const float* __restrict__ Wk,
    const float* __restrict__ Wv, unsigned short* __restrict__ Wt)
{
    __shared__ __attribute__((aligned(16))) unsigned short tw[64 * 132];
    const int w = blockIdx.y;
    const int k0 = blockIdx.x * 64;
    const float* W = (w == 0) ? Wq : (w == 1) ? Wk : Wv;
    const int tid = threadIdx.x;
#pragma unroll
    for (int p = 0; p < 8; p++) {
        const int f = p * 256 + tid;        // float4 index over 64x32
        const int row = f >> 5, c4 = f & 31;
        const float4 v = *(const float4*)&W[(size_t)(k0 + row) * HD_D + c4 * 4];
        ushort4v h = { f2bf_rne(v.x), f2bf_rne(v.y), f2bf_rne(v.z), f2bf_rne(v.w) };
        *(ushort4v*)&tw[row * 132 + c4 * 4] = h;
    }
    __syncthreads();
    const int n = tid >> 1, h = tid & 1;    // n: 0..127, h: k-half
    unsigned short* dst = Wt + (size_t)w * (HD_D * EMB_D) + (size_t)n * EMB_D + k0 + h * 32;
#pragma unroll
    for (int j = 0; j < 4; j++) {
        ushort8v o;
#pragma unroll
        for (int jj = 0; jj < 8; jj++) o[jj] = tw[(h * 32 + j * 8 + jj) * 132 + n];
        *(ushort8v*)&dst[j * 8] = o;
    }
}

// ---------------------------------------------------------------------------
// Kernel 1: QKV projection + RoPE. Tile 32(M) x 128(N), BK=64.
//   grid (3, 256): w fastest so same-m blocks share x in L2. 768 blocks.
//   Q pre-scaled by log2(e)/sqrt(128) (exp2 domain). V stored Vt[b][d][t].
// ---------------------------------------------------------------------------
__global__ __launch_bounds__(256) void qkv_rope(
    const float* __restrict__ x, const unsigned short* __restrict__ Wt,
    const float* __restrict__ rcos, const float* __restrict__ rsin,
    unsigned short* __restrict__ Qb, unsigned short* __restrict__ Kb,
    unsigned short* __restrict__ Vt)
{
    __shared__ __attribute__((aligned(16))) unsigned short xa[32 * 72]; // pad 72: 2-way only
    const int w   = blockIdx.x;
    const int m0  = blockIdx.y * 32;
    const int tid = threadIdx.x;
    const int lane = tid & 63, wave = tid >> 6;
    const int l15 = lane & 15, lq = lane >> 4;
    const int kf = lq * 8;
    const unsigned short* Wb = Wt + (size_t)w * (HD_D * EMB_D);

    f32x4 acc[2][2];
#pragma unroll
    for (int i = 0; i < 2; i++)
#pragma unroll
        for (int j = 0; j < 2; j++) acc[i][j] = (f32x4){0.f, 0.f, 0.f, 0.f};

    for (int k0 = 0; k0 < EMB_D; k0 += 64) {
        __syncthreads();
#pragma unroll
        for (int p = 0; p < 2; p++) {
            const int f = p * 256 + tid;    // float4 index over 32x16
            const int row = f >> 4, c4 = f & 15;
            const float4 v = *(const float4*)&x[(size_t)(m0 + row) * EMB_D + k0 + c4 * 4];
            ushort4v h = { f2bf_fast(v.x), f2bf_fast(v.y), f2bf_fast(v.z), f2bf_fast(v.w) };
            *(ushort4v*)&xa[row * 72 + c4 * 4] = h;
        }
        __syncthreads();
        short8 aF[2][2], bF[2][2];
#pragma unroll
        for (int i = 0; i < 2; i++)
#pragma unroll
            for (int ks = 0; ks < 2; ks++)
                aF[i][ks] = *(const short8*)&xa[(i * 16 + l15) * 72 + ks * 32 + kf];
#pragma unroll
        for (int j = 0; j < 2; j++)
#pragma unroll
            for (int ks = 0; ks < 2; ks++)
                bF[j][ks] = *(const short8*)&Wb[(size_t)(wave * 32 + j * 16 + l15) * EMB_D + k0 + ks * 32 + kf];
#pragma unroll
        for (int ks = 0; ks < 2; ks++)
#pragma unroll
            for (int i = 0; i < 2; i++)
#pragma unroll
                for (int j = 0; j < 2; j++)
                    acc[i][j] = __builtin_amdgcn_mfma_f32_16x16x32_bf16(aF[i][ks], bF[j][ks], acc[i][j], 0, 0, 0);
    }

    // Epilogue: C layout row=lq*4+reg, col=l15
    const float qscale = 0.08838834764831845f * 1.4426950408889634f; // 1/sqrt(128)*log2(e)
#pragma unroll
    for (int i = 0; i < 2; i++) {
#pragma unroll
        for (int r = 0; r < 4; r++) {
            const int row = m0 + i * 16 + lq * 4 + r;   // b*T + t
            const int t = row & (T_SEQ - 1);
#pragma unroll
            for (int j = 0; j < 2; j++) {
                const int col = wave * 32 + j * 16 + l15;
                const float v = acc[i][j][r];
                if (w == 2) {
                    const int bb = row >> 11;
                    Vt[((size_t)bb * HD_D + col) * T_SEQ + t] = f2bf_rne(v);
                } else {
                    const int ip = col >> 1;
                    const float c = rcos[t * 64 + ip];
                    const float s = rsin[t * 64 + ip];
                    const float pv = __shfl_xor(v, 1);
                    float rv = (col & 1) ? (pv * s + v * c) : (v * c - pv * s);
                    if (w == 0) rv *= qscale;
                    const unsigned short o = f2bf_rne(rv);
                    if (w == 0) Qb[(size_t)row * HD_D + col] = o;
                    else        Kb[(size_t)row * HD_D + col] = o;
                }
            }
        }
    }
}

// ---------------------------------------------------------------------------
// Kernel 2: flash attention, causal, online softmax, exp2 domain.
//   grid (512): idx -> b = idx&3, q-tile reversed (heavy blocks first).
//   4 waves/block split the k-range (strided 64-key chunks), LSE-merged in LDS.
// ---------------------------------------------------------------------------
__global__ __launch_bounds__(256) void attn(
    const unsigned short* __restrict__ Qb, const unsigned short* __restrict__ Kb,
    const unsigned short* __restrict__ Vt, float* __restrict__ out)
{
    __shared__ __attribute__((aligned(16))) unsigned short P_s[4][16 * 72];
    __shared__ f32x4 O_s4[512];                 // 16 x 128 fp32
    __shared__ float m_s[4][16], l_s[4][16], lst[16];
    float* O_s = (float*)O_s4;

    const int tid = threadIdx.x;
    const int lane = tid & 63, wave = tid >> 6;
    const int l15 = lane & 15, lq = lane >> 4;
    const int kf = lq * 8;

    const int idx = blockIdx.x;
    const int b  = idx & 3;
    const int q0 = (127 - (idx >> 2)) * 16;     // heavy q-tiles dispatched first
    const int kend = q0 + 16;

    const unsigned short* Qp = Qb + (size_t)(b * T_SEQ + q0) * HD_D;
    short8 aQ[4];
#pragma unroll
    for (int d = 0; d < 4; d++)
        aQ[d] = *(const short8*)&Qp[l15 * HD_D + d * 32 + kf];

    f32x4 acc[8];
#pragma unroll
    for (int d = 0; d < 8; d++) acc[d] = (f32x4){0.f, 0.f, 0.f, 0.f};
    float m_r[4] = {-1e30f, -1e30f, -1e30f, -1e30f};
    float l_r[4] = {0.f, 0.f, 0.f, 0.f};

    const unsigned short* Kbase = Kb + (size_t)b * T_SEQ * HD_D;
    const unsigned short* Vbase = Vt + (size_t)b * HD_D * T_SEQ;
    unsigned short* Pw = &P_s[wave][0];

    // zero O accumulator while the k-loop is still to come (before barrier)
#pragma unroll
    for (int p = 0; p < 2; p++) O_s4[p * 256 + tid] = (f32x4){0.f, 0.f, 0.f, 0.f};

    for (int c = wave; c * 64 < kend; c += 4) {
        const int k0 = c * 64;
        f32x4 s[4];
#pragma unroll
        for (int n = 0; n < 4; n++) s[n] = (f32x4){0.f, 0.f, 0.f, 0.f};
        const unsigned short* Kp = Kbase + (size_t)k0 * HD_D;
#pragma unroll
        for (int d = 0; d < 4; d++) {
#pragma unroll
            for (int n = 0; n < 4; n++) {
                short8 bK = *(const short8*)&Kp[(size_t)(n * 16 + l15) * HD_D + d * 32 + kf];
                s[n] = __builtin_amdgcn_mfma_f32_16x16x32_bf16(aQ[d], bK, s[n], 0, 0, 0);
            }
        }
        float al[4];
#pragma unroll
        for (int r = 0; r < 4; r++) {
            const int q = q0 + lq * 4 + r;
            float vm[4]; bool va[4];
#pragma unroll
            for (int n = 0; n < 4; n++) {
                va[n] = (k0 + n * 16 + l15) <= q;
                vm[n] = va[n] ? s[n][r] : -1e30f;
            }
            float t = fmaxf(fmaxf(vm[0], vm[1]), fmaxf(vm[2], vm[3]));
            t = fmaxf(t, __shfl_xor(t, 1));
            t = fmaxf(t, __shfl_xor(t, 2));
            t = fmaxf(t, __shfl_xor(t, 4));
            t = fmaxf(t, __shfl_xor(t, 8));
            const float mn = fmaxf(m_r[r], t);
            al[r] = EXP2F(m_r[r] - mn);
            float p[4], rs = 0.f;
#pragma unroll
            for (int n = 0; n < 4; n++) {
                p[n] = va[n] ? EXP2F(vm[n] - mn) : 0.f;   // select guards all-masked chunks
                rs += p[n];
            }
            rs += __shfl_xor(rs, 1);
            rs += __shfl_xor(rs, 2);
            rs += __shfl_xor(rs, 4);
            rs += __shfl_xor(rs, 8);
            l_r[r] = l_r[r] * al[r] + rs;
            m_r[r] = mn;
            const int prow = (lq * 4 + r) * 72;
#pragma unroll
            for (int n = 0; n < 4; n++) Pw[prow + n * 16 + l15] = f2bf_fast(p[n]);
        }
#pragma unroll
        for (int d = 0; d < 8; d++)
#pragma unroll
            for (int r = 0; r < 4; r++) acc[d][r] *= al[r];
#pragma unroll
        for (int ks = 0; ks < 2; ks++) {
            const short8 pA = *(const short8*)&Pw[l15 * 72 + ks * 32 + kf];
#pragma unroll
            for (int d = 0; d < 8; d++) {
                short8 bV = *(const short8*)&Vbase[(size_t)(d * 16 + l15) * T_SEQ + k0 + ks * 32 + kf];
                acc[d] = __builtin_amdgcn_mfma_f32_16x16x32_bf16(pA, bV, acc[d], 0, 0, 0);
            }
        }
    }

    // ---- LSE merge across the 4 k-split waves ----
    if (l15 == 0) {
#pragma unroll
        for (int r = 0; r < 4; r++) {
            m_s[wave][lq * 4 + r] = m_r[r];
            l_s[wave][lq * 4 + r] = l_r[r];
        }
    }
    __syncthreads();
#pragma unroll
    for (int r = 0; r < 4; r++) {
        const int row = lq * 4 + r;
        const float mm = fmaxf(fmaxf(m_s[0][row], m_s[1][row]),
                               fmaxf(m_s[2][row], m_s[3][row]));
        const float sc = (l_r[r] == 0.f) ? 0.f : EXP2F(m_r[r] - mm);
#pragma unroll
        for (int d = 0; d < 8; d++)
            atomicAdd(&O_s[row * 128 + d * 16 + l15], acc[d][r] * sc);
        if (wave == 0 && l15 == 0) {
            float ls = 0.f;
#pragma unroll
            for (int w2 = 0; w2 < 4; w2++) {
                const float lw = l_s[w2][row];
                if (lw != 0.f) ls += EXP2F(m_s[w2][row] - mm) * lw;
            }
            lst[row] = ls;
        }
    }
    __syncthreads();
    float* op = out + (size_t)(b * T_SEQ + q0) * HD_D;
#pragma unroll
    for (int p = 0; p < 2; p++) {
        const int f = p * 256 + tid;        // float4 index over 16x32
        const int row = f >> 5, c4 = f & 31;
        f32x4 v = O_s4[f];
        const float inv = 1.0f / lst[row];
        *(f32x4*)&op[(size_t)row * HD_D + c4 * 4] = v * inv;
    }
}

// ---------------------------------------------------------------------------
extern "C" void kernel_launch(void* const* d_in, const int* in_sizes, int n_in,
                              void* d_out, int out_size, void* d_ws, size_t ws_size,
                              hipStream_t stream)
{
    (void)in_sizes; (void)n_in; (void)out_size; (void)ws_size;
    const float* x  = (const float*)d_in[0];
    const float* Wq = (const float*)d_in[1];
    const float* Wk = (const float*)d_in[2];
    const float* Wv = (const float*)d_in[3];
    const float* rc = (const float*)d_in[4];
    const float* rs = (const float*)d_in[5];
    // d_in[6] = additive causal mask: handled analytically, not read.
    float* out = (float*)d_out;

    char* ws = (char*)d_ws;
    unsigned short* Wt = (unsigned short*)(ws);
    unsigned short* Qb = (unsigned short*)(ws + 1572864);
    unsigned short* Kb = (unsigned short*)(ws + 1572864 + 2097152);
    unsigned short* Vt = (unsigned short*)(ws + 1572864 + 2 * 2097152);

    prep_weights<<<dim3(32, 3),  256, 0, stream>>>(Wq, Wk, Wv, Wt);
    qkv_rope    <<<dim3(3, 256), 256, 0, stream>>>(x, Wt, rc, rs, Qb, Kb, Vt);
    attn        <<<dim3(512),    256, 0, stream>>>(Qb, Kb, Vt, out);
}